// Round 16
// baseline (66.875 us; speedup 1.0000x reference)
//
#include <hip/hip_runtime.h>
#include <hip/hip_bf16.h>

// FactorizedTrilinear: out[b,z,x,c,dv] = sum_e p1[b,z,dv,e] p2[b,x,dv,e] p3[b,c,dv,e]
// B=4, Z=128, DV=4, IN=512, R=256. Output 4*128^3*4 fp32 = 134 MB.
// R16: (1) proj v4 solo — 16x16x32 MFMA, 64m x 16n tiles, grid (32,16,3) =
// 1536 blocks = exactly 6/CU (R15 proj ran 384 blocks = 1.5/CU -> 2 rounds).
// (2) tri = R15 verbatim EXCEPT grid remap: ct,xt fastest so the ~512 resident
// blocks co-write contiguous 2 MB slabs (HBM write page locality; zg-fastest
// scattered writes across all 134 MB and may explain 3.4 vs 6.9 TB/s).

typedef _Float16 f16;
typedef __attribute__((ext_vector_type(8)))  _Float16 f16x8;
typedef __attribute__((ext_vector_type(4)))  float    f32x4;
typedef __attribute__((ext_vector_type(16))) float    f32x16;

// LDS-only barrier: waits local ds ops, does NOT drain global loads/stores.
__device__ __forceinline__ void lds_barrier() {
    __builtin_amdgcn_sched_barrier(0);
    asm volatile("s_waitcnt lgkmcnt(0)" ::: "memory");
    __builtin_amdgcn_s_barrier();
    __builtin_amdgcn_sched_barrier(0);
}

// ---------------- Stage 1: projections via 16x16x32 f16 MFMA ----------------
// GEMM per matrix: M=2048 (m = b*512 + z*4 + dv), N=256, K=512.
// Block 256 thr = 4 waves stacked in m -> tile 64m x 16n; grid (32,16,3) = 1536
// blocks = 6/CU exact. 8 chunks of 64k: stage W[64k][16n] -> sWt[n][k] f16
// (row stride 72), one f32x4 W load per thread per chunk.
__global__ __launch_bounds__(256) void proj_kernel(
    const float* __restrict__ x1, const float* __restrict__ x2, const float* __restrict__ x3,
    const float* __restrict__ W1, const float* __restrict__ b1,
    const float* __restrict__ W2, const float* __restrict__ b2,
    const float* __restrict__ W3, const float* __restrict__ b3,
    f16* __restrict__ p1, f16* __restrict__ p2, f16* __restrict__ p3) {
    const int mat = blockIdx.z;
    const float* __restrict__ x    = (mat == 0) ? x1 : (mat == 1) ? x2 : x3;
    const float* __restrict__ W    = (mat == 0) ? W1 : (mat == 1) ? W2 : W3;
    const float* __restrict__ bias = (mat == 0) ? b1 : (mat == 1) ? b2 : b3;
    f16* __restrict__ p = (mat == 0) ? p1 : (mat == 1) ? p2 : p3;

    const int tid  = threadIdx.x;
    const int lane = tid & 63;
    const int w    = tid >> 6;
    const int ln   = lane & 15;         // n within 16
    const int kq   = lane >> 4;         // k-quarter (4 x 8)
    const int m0   = blockIdx.x * 64 + w * 16;
    const int n0   = blockIdx.y * 16;
    const int n    = n0 + ln;

    __shared__ f16 sWt[16 * 72];        // [n][k], row stride 72 f16 (2.3 KB)

    f32x4 acc = (f32x4){0.f, 0.f, 0.f, 0.f};

    const int kk = tid >> 2, nq = tid & 3;   // staging granule

#pragma unroll 1
    for (int ch = 0; ch < 8; ++ch) {
        const int k0 = ch * 64;
        // stage W chunk: [64k][16n] -> sWt[n][k], one f32x4 per thread
        f32x4 wv = *(const f32x4*)(W + (size_t)(k0 + kk) * 256 + n0 + nq * 4);
#pragma unroll
        for (int i = 0; i < 4; ++i)
            sWt[(nq * 4 + i) * 72 + kk] = (f16)wv[i];
        __syncthreads();
#pragma unroll
        for (int kss = 0; kss < 2; ++kss) {
            const float* X = x + (size_t)(m0 + ln) * 512 + k0 + kss * 32 + kq * 8;
            f32x4 a0 = *(const f32x4*)X;
            f32x4 a1 = *(const f32x4*)(X + 4);
            f16x8 av;
            av[0] = (f16)a0[0]; av[1] = (f16)a0[1]; av[2] = (f16)a0[2]; av[3] = (f16)a0[3];
            av[4] = (f16)a1[0]; av[5] = (f16)a1[1]; av[6] = (f16)a1[2]; av[7] = (f16)a1[3];
            f16x8 bv = *(const f16x8*)&sWt[ln * 72 + kss * 32 + kq * 8];
            acc = __builtin_amdgcn_mfma_f32_16x16x32_f16(av, bv, acc, 0, 0, 0);
        }
        __syncthreads();
    }

    // C map (verified): row m = (lane>>4)*4 + reg, col n = lane&15.
    const float bn = bias[n];
#pragma unroll
    for (int r = 0; r < 4; ++r) {
        const int m  = m0 + kq * 4 + r;
        const int bb = m >> 9, z = (m >> 2) & 127, dv = m & 3;
        p[((bb * 4 + dv) * 128 + z) * 256 + n] = (f16)(acc[r] + bn);
    }
}

// ---------------- Stage 2: trilinear (R15 structure, write-locality grid) ----------------
// Grid 1024 blocks, bi = b*256 + zg*16 + xt*4 + ct (ct,xt FASTEST): the 16
// consecutively-dispatched blocks per (b,zg) co-write one contiguous 2 MB slab.
// 256 thr = 4 waves, wave w = dv. Wave: 32x x 32c x 8z x 1dv.
// pv[16]+bq[16] full-K register-resident; sP1 wave-private; per z: 16 MFMA ->
// sT[zi&1] (stride 33) -> lgkm-only barrier -> f32x4-over-dv PLAIN stores
// (no vmcnt anywhere in the loop).
__global__ __launch_bounds__(256, 2) void tri_kernel(
    const f16* __restrict__ p1, const f16* __restrict__ p2,
    const f16* __restrict__ p3, float* __restrict__ out) {
    const int bi = blockIdx.x;
    const int ct = bi & 3;
    const int xt = (bi >> 2) & 3;
    const int zg = (bi >> 4) & 15;
    const int b  = bi >> 8;

    const int tid  = threadIdx.x;
    const int lane = tid & 63;
    const int w    = tid >> 6;          // = dv
    const int ln   = lane & 31;
    const int kq   = lane >> 5;
    const int x0   = xt * 32;
    const int c0   = ct * 32;
    const int z0   = zg * 8;
    const int sl   = b * 4 + w;

    __shared__ __align__(16) f16  sP1[4][8 * 256];   // 16 KB, wave-private p1 rows
    __shared__ float sT[2][4 * 32 * 33];             // 2 x 16.5 KB transpose buffers

    // ---- stage this wave's p1 z-rows (wave-private: no barrier) ----
#pragma unroll
    for (int i = 0; i < 4; ++i) {
        const int G  = i * 64 + lane;
        const int zo = G >> 5, es = G & 31;
        f16x8 v = *(const f16x8*)(p1 + ((sl * 128 + z0 + zo) << 8) + es * 8);
        *(f16x8*)&sP1[w][G * 8] = v;
    }

    // ---- prologue: full-K fragments in registers (z-invariant) ----
    f16x8 pv[16], bq[16];
    const f16* P2r = p2 + ((sl * 128 + x0 + ln) << 8) + kq * 8;
    const f16* P3r = p3 + ((sl * 128 + c0 + ln) << 8) + kq * 8;
#pragma unroll
    for (int ks = 0; ks < 16; ++ks) {
        pv[ks] = *(const f16x8*)(P2r + ks * 16);
        bq[ks] = *(const f16x8*)(P3r + ks * 16);
    }

    const int cl = tid & 31, xg = tid >> 5;

#pragma unroll 1
    for (int zi = 0; zi < 8; ++zi) {
        f32x16 acc;
#pragma unroll
        for (int i = 0; i < 16; ++i) acc[i] = 0.f;

#pragma unroll
        for (int ks = 0; ks < 16; ++ks) {
            f16x8 u = *(const f16x8*)&sP1[w][(zi * 32 + ks * 2 + kq) * 8];  // broadcast
            f16x8 af = u * pv[ks];        // 4x v_pk_mul_f16
            acc = __builtin_amdgcn_mfma_f32_32x32x16_f16(af, bq[ks], acc, 0, 0, 0);
        }

        // ---- acc -> LDS sT[zi&1][dv][x][c] (stride 33: conflict-free) ----
        float* T = sT[zi & 1];
#pragma unroll
        for (int i = 0; i < 16; ++i) {
            const int xl = (i & 3) + 8 * (i >> 2) + 4 * kq;
            T[w * 1056 + xl * 33 + ln] = acc[i];
        }
        lds_barrier();   // lgkm only: stores from prior iters keep draining

        // ---- transposed read + coalesced f32x4-over-dv PLAIN stores ----
        const int z = z0 + zi;
#pragma unroll
        for (int j = 0; j < 4; ++j) {
            const int xl = xg * 4 + j;
            f32x4 v;
            v[0] = T[0 * 1056 + xl * 33 + cl];
            v[1] = T[1 * 1056 + xl * 33 + cl];
            v[2] = T[2 * 1056 + xl * 33 + cl];
            v[3] = T[3 * 1056 + xl * 33 + cl];
            const size_t idx = (size_t)((b * 128 + z) * 128 + x0 + xl) * 128 + c0 + cl;
            *(f32x4*)(out + idx * 4) = v;   // plain store: L2 write-back path
        }
        // no second barrier: next iter writes the other sT buffer.
    }
}

extern "C" void kernel_launch(void* const* d_in, const int* in_sizes, int n_in,
                              void* d_out, int out_size, void* d_ws, size_t ws_size,
                              hipStream_t stream) {
    const float* x1 = (const float*)d_in[0];
    const float* x2 = (const float*)d_in[1];
    const float* x3 = (const float*)d_in[2];
    const float* W1 = (const float*)d_in[3];
    const float* b1 = (const float*)d_in[4];
    const float* W2 = (const float*)d_in[5];
    const float* b2 = (const float*)d_in[6];
    const float* W3 = (const float*)d_in[7];
    const float* b3 = (const float*)d_in[8];

    char* ws = (char*)d_ws;
    f16* p1 = (f16*)ws;                            // [16][128][256] f16 = 1 MB
    f16* p2 = (f16*)(ws + (1u << 20));             // 1 MB
    f16* p3 = (f16*)(ws + 2u * (1u << 20));        // 1 MB

    proj_kernel<<<dim3(32, 16, 3), 256, 0, stream>>>(x1, x2, x3, W1, b1, W2, b2, W3, b3,
                                                     p1, p2, p3);
    tri_kernel<<<dim3(1024), 256, 0, stream>>>(p1, p2, p3, (float*)d_out);
}

// Round 17
// 53.024 us; speedup vs baseline: 1.2612x; 1.2612x over previous
//
#include <hip/hip_runtime.h>
#include <hip/hip_bf16.h>

// FactorizedTrilinear: out[b,z,x,c,dv] = sum_e p1[b,z,dv,e] p2[b,x,dv,e] p3[b,c,dv,e]
// B=4, Z=128, DV=4, IN=512, R=256. Output 4*128^3*4 fp32 = 134 MB.
// R17: tri = R15 VERBATIM (best: 57.6 total, tri ~42). proj = R15's prefetch
// structure re-tiled 64m x 32n, 128-thr blocks (2 waves split m), grid (32,8,3)
// = 768 blocks = exactly 3/CU (R15's 384 = 1.5/CU made half the CUs run 2
// rounds). Per-thread staging/MFMA identical to R15. [R16 attribution: proj-v4
// 16x16 tiles = +9 us (2 regressions), tri ct/xt remap = neutral -> reverted.]

typedef _Float16 f16;
typedef __attribute__((ext_vector_type(8)))  _Float16 f16x8;
typedef __attribute__((ext_vector_type(4)))  float    f32x4;
typedef __attribute__((ext_vector_type(16))) float    f32x16;

// LDS-only barrier: waits local ds ops, does NOT drain global loads/stores.
__device__ __forceinline__ void lds_barrier() {
    __builtin_amdgcn_sched_barrier(0);
    asm volatile("s_waitcnt lgkmcnt(0)" ::: "memory");
    __builtin_amdgcn_s_barrier();
    __builtin_amdgcn_sched_barrier(0);
}

// ---------------- Stage 1: projections via 32x32x16 f16 MFMA ----------------
// GEMM per matrix: M=2048 (m = b*512 + z*4 + dv), N=256, K=512.
// Block 128 thr = 2 waves (m-split) -> tile 64m x 32n; grid (32,8,3) = 768
// blocks = 3/CU exact. 16 chunks of 32k, double-buffered sWt[n][k] (stride 40);
// W (8 scalars) + x (16 floats) for chunk ch+1 prefetched into registers during
// chunk ch's MFMA; one lgkm-only barrier per chunk.
__global__ __launch_bounds__(128) void proj_kernel(
    const float* __restrict__ x1, const float* __restrict__ x2, const float* __restrict__ x3,
    const float* __restrict__ W1, const float* __restrict__ b1,
    const float* __restrict__ W2, const float* __restrict__ b2,
    const float* __restrict__ W3, const float* __restrict__ b3,
    f16* __restrict__ p1, f16* __restrict__ p2, f16* __restrict__ p3) {
    const int mat = blockIdx.z;
    const float* __restrict__ x    = (mat == 0) ? x1 : (mat == 1) ? x2 : x3;
    const float* __restrict__ W    = (mat == 0) ? W1 : (mat == 1) ? W2 : W3;
    const float* __restrict__ bias = (mat == 0) ? b1 : (mat == 1) ? b2 : b3;
    f16* __restrict__ p = (mat == 0) ? p1 : (mat == 1) ? p2 : p3;

    const int tid  = threadIdx.x;
    const int lane = tid & 63;
    const int w    = tid >> 6;          // wave = m-half
    const int ln   = lane & 31;
    const int kq   = lane >> 5;
    const int m0   = blockIdx.x * 64 + w * 32;
    const int n0b  = blockIdx.y * 32;

    __shared__ f16 sWt[2][32 * 40];     // dbuf [n][k], stride 40 f16 (2 x 2.5 KB)

    f32x16 acc;
#pragma unroll
    for (int i = 0; i < 16; ++i) acc[i] = 0.f;

    const int snn = tid & 31, skk0 = tid >> 5;   // staging: n, k-phase (0..3)
    const float* Xr = x + (size_t)(m0 + ln) * 512 + kq * 8;

    // ---- prologue: chunk 0's W and x in registers ----
    float wr[8], wr2[8];
    f32x4 xr[4], xn[4];
#pragma unroll
    for (int j = 0; j < 8; ++j)
        wr[j] = W[(size_t)(skk0 + 4 * j) * 256 + n0b + snn];
#pragma unroll
    for (int t = 0; t < 2; ++t) {
        xr[2 * t]     = *(const f32x4*)(Xr + t * 16);
        xr[2 * t + 1] = *(const f32x4*)(Xr + t * 16 + 4);
    }

#pragma unroll 1
    for (int ch = 0; ch < 16; ++ch) {
        const int buf = ch & 1;
        // write staged W regs -> LDS buffer `buf`
#pragma unroll
        for (int j = 0; j < 8; ++j)
            sWt[buf][snn * 40 + skk0 + 4 * j] = (f16)wr[j];
        // prefetch chunk ch+1 (W + x) into registers
        if (ch < 15) {
            const int k1 = (ch + 1) * 32;
#pragma unroll
            for (int j = 0; j < 8; ++j)
                wr2[j] = W[(size_t)(k1 + skk0 + 4 * j) * 256 + n0b + snn];
#pragma unroll
            for (int t = 0; t < 2; ++t) {
                xn[2 * t]     = *(const f32x4*)(Xr + k1 + t * 16);
                xn[2 * t + 1] = *(const f32x4*)(Xr + k1 + t * 16 + 4);
            }
        }
        lds_barrier();   // lgkm only: prefetch loads stay in flight
        // MFMA on buffer `buf`
#pragma unroll
        for (int ks = 0; ks < 2; ++ks) {
            f32x4 a0 = xr[2 * ks], a1 = xr[2 * ks + 1];
            f16x8 av;
            av[0] = (f16)a0[0]; av[1] = (f16)a0[1]; av[2] = (f16)a0[2]; av[3] = (f16)a0[3];
            av[4] = (f16)a1[0]; av[5] = (f16)a1[1]; av[6] = (f16)a1[2]; av[7] = (f16)a1[3];
            f16x8 bv = *(const f16x8*)&sWt[buf][ln * 40 + ks * 16 + kq * 8];
            acc = __builtin_amdgcn_mfma_f32_32x32x16_f16(av, bv, acc, 0, 0, 0);
        }
        // rotate prefetch regs
#pragma unroll
        for (int t = 0; t < 4; ++t) xr[t] = xn[t];
#pragma unroll
        for (int j = 0; j < 8; ++j) wr[j] = wr2[j];
        // no second barrier: next chunk writes the other sWt buffer
    }

    // C/D map (m74/m101): col = lane&31 -> n, row = (i&3)+8*(i>>2)+4*kq -> m.
    const int n = n0b + ln;
    const float bn = bias[n];
#pragma unroll
    for (int i = 0; i < 16; ++i) {
        const int m  = m0 + (i & 3) + 8 * (i >> 2) + 4 * kq;
        const int bb = m >> 9, z = (m >> 2) & 127, dv = m & 3;
        p[((bb * 4 + dv) * 128 + z) * 256 + n] = (f16)(acc[i] + bn);
    }
}

// ---------------- Stage 2: trilinear (R15 verbatim) ----------------
// Grid = b(4) x xt(4) x ct(4) x zg(16), zg fastest = 1024 blocks; 256 thr =
// 4 waves, wave w = dv. Wave: 32x x 32c x 8z x 1dv.
// pv[16] (p2 x-rows), bq[16] (p3 c-rows): full K=256 in 128 VGPRs, z-invariant.
// p1 z-rows staged in wave-private sP1. Per z: 16 MFMA -> sT[zi&1][dv][x][c]
// (stride 33) -> lgkm-only barrier -> transposed f32x4-over-dv PLAIN stores
// (drain under next iter's MFMA; no vmcnt in loop).
__global__ __launch_bounds__(256, 2) void tri_kernel(
    const f16* __restrict__ p1, const f16* __restrict__ p2,
    const f16* __restrict__ p3, float* __restrict__ out) {
    const int bi = blockIdx.x;
    const int zg = bi & 15;
    const int ct = (bi >> 4) & 3;
    const int xt = (bi >> 6) & 3;
    const int b  = bi >> 8;

    const int tid  = threadIdx.x;
    const int lane = tid & 63;
    const int w    = tid >> 6;          // = dv
    const int ln   = lane & 31;
    const int kq   = lane >> 5;
    const int x0   = xt * 32;
    const int c0   = ct * 32;
    const int z0   = zg * 8;
    const int sl   = b * 4 + w;

    __shared__ __align__(16) f16  sP1[4][8 * 256];   // 16 KB, wave-private p1 rows
    __shared__ float sT[2][4 * 32 * 33];             // 2 x 16.5 KB transpose buffers

    // ---- stage this wave's p1 z-rows (wave-private: no barrier) ----
#pragma unroll
    for (int i = 0; i < 4; ++i) {
        const int G  = i * 64 + lane;
        const int zo = G >> 5, es = G & 31;
        f16x8 v = *(const f16x8*)(p1 + ((sl * 128 + z0 + zo) << 8) + es * 8);
        *(f16x8*)&sP1[w][G * 8] = v;
    }

    // ---- prologue: full-K fragments in registers (z-invariant) ----
    f16x8 pv[16], bq[16];
    const f16* P2r = p2 + ((sl * 128 + x0 + ln) << 8) + kq * 8;
    const f16* P3r = p3 + ((sl * 128 + c0 + ln) << 8) + kq * 8;
#pragma unroll
    for (int ks = 0; ks < 16; ++ks) {
        pv[ks] = *(const f16x8*)(P2r + ks * 16);
        bq[ks] = *(const f16x8*)(P3r + ks * 16);
    }

    const int cl = tid & 31, xg = tid >> 5;

#pragma unroll 1
    for (int zi = 0; zi < 8; ++zi) {
        f32x16 acc;
#pragma unroll
        for (int i = 0; i < 16; ++i) acc[i] = 0.f;

#pragma unroll
        for (int ks = 0; ks < 16; ++ks) {
            f16x8 u = *(const f16x8*)&sP1[w][(zi * 32 + ks * 2 + kq) * 8];  // broadcast
            f16x8 af = u * pv[ks];        // 4x v_pk_mul_f16
            acc = __builtin_amdgcn_mfma_f32_32x32x16_f16(af, bq[ks], acc, 0, 0, 0);
        }

        // ---- acc -> LDS sT[zi&1][dv][x][c] (stride 33: conflict-free) ----
        float* T = sT[zi & 1];
#pragma unroll
        for (int i = 0; i < 16; ++i) {
            const int xl = (i & 3) + 8 * (i >> 2) + 4 * kq;
            T[w * 1056 + xl * 33 + ln] = acc[i];
        }
        lds_barrier();   // lgkm only: stores from prior iters keep draining

        // ---- transposed read + coalesced f32x4-over-dv PLAIN stores ----
        const int z = z0 + zi;
#pragma unroll
        for (int j = 0; j < 4; ++j) {
            const int xl = xg * 4 + j;
            f32x4 v;
            v[0] = T[0 * 1056 + xl * 33 + cl];
            v[1] = T[1 * 1056 + xl * 33 + cl];
            v[2] = T[2 * 1056 + xl * 33 + cl];
            v[3] = T[3 * 1056 + xl * 33 + cl];
            const size_t idx = (size_t)((b * 128 + z) * 128 + x0 + xl) * 128 + c0 + cl;
            *(f32x4*)(out + idx * 4) = v;   // plain store: L2 write-back path
        }
        // no second barrier: next iter writes the other sT buffer.
    }
}

extern "C" void kernel_launch(void* const* d_in, const int* in_sizes, int n_in,
                              void* d_out, int out_size, void* d_ws, size_t ws_size,
                              hipStream_t stream) {
    const float* x1 = (const float*)d_in[0];
    const float* x2 = (const float*)d_in[1];
    const float* x3 = (const float*)d_in[2];
    const float* W1 = (const float*)d_in[3];
    const float* b1 = (const float*)d_in[4];
    const float* W2 = (const float*)d_in[5];
    const float* b2 = (const float*)d_in[6];
    const float* W3 = (const float*)d_in[7];
    const float* b3 = (const float*)d_in[8];

    char* ws = (char*)d_ws;
    f16* p1 = (f16*)ws;                            // [16][128][256] f16 = 1 MB
    f16* p2 = (f16*)(ws + (1u << 20));             // 1 MB
    f16* p3 = (f16*)(ws + 2u * (1u << 20));        // 1 MB

    proj_kernel<<<dim3(32, 8, 3), 128, 0, stream>>>(x1, x2, x3, W1, b1, W2, b2, W3, b3,
                                                    p1, p2, p3);
    tri_kernel<<<dim3(1024), 256, 0, stream>>>(p1, p2, p3, (float*)d_out);
}